// Round 13
// baseline (477.308 us; speedup 1.0000x reference)
//
#include <hip/hip_runtime.h>

#define AA 256
#define EE 256
#define CC (AA + EE + AA*EE)   // 66048
#define TT 1024
#define VV 1024
#define NSTRIP 16
#define NCHUNKS 36             // 36 chunks x 16 supersteps = 576 supersteps
#define SSTRIDE ((size_t)1024 * 64)   // strip-local col-major: [col][lane]
#define NEGBIG (-3.0e38f)      // finite stand-in for -inf in outputs
#define INVLN2 1.44269504088896340736f
#define LN2F   0.69314718055994530942f
#define SENT   0x7FC00001u     // NaN-payload sentinel for bnd
#define NINF   (-__builtin_inff())

#define E2(x) __builtin_amdgcn_exp2f(x)  // native v_exp_f32: 2^x
#define L2(x) __builtin_amdgcn_logf(x)   // native v_log_f32: log2(x)

// order-preserving float->uint key for atomicMax
__device__ __forceinline__ unsigned fkey(float f) {
    unsigned u = __float_as_uint(f);
    return (u & 0x80000000u) ? ~u : (u | 0x80000000u);
}
__device__ __forceinline__ float fdec(unsigned k) {
    return __uint_as_float((k & 0x80000000u) ? (k & 0x7FFFFFFFu) : ~k);
}
#define KEY_NEGINF 0x007FFFFFu   // fkey(-inf)

__device__ __forceinline__ float safe_out(float v) {
    if (!(v > NEGBIG)) return NEGBIG;   // catches -inf, NaN
    return v;
}

__device__ __forceinline__ float lse3(float x, float y, float z) {
    float m3 = fmaxf(fmaxf(x, y), z);
    float me = __builtin_amdgcn_fmed3f(x, y, z);
    float mn = fminf(fminf(x, y), z);
    return m3 + L2(1.0f + E2(me - m3) + E2(mn - m3));
}

// ---------------- init: bins + bnd sentinel + W2 = W/ln2 ----------------
__global__ void k_init(const float* __restrict__ W, float* __restrict__ W2,
                       unsigned* __restrict__ mkey, float* __restrict__ sbuf,
                       unsigned* __restrict__ bndu) {
    int i = blockIdx.x * 256 + threadIdx.x;
    if (i < CC) { mkey[i] = 0u; sbuf[i] = 0.0f; W2[i] = W[i] * INVLN2; }
    if (i < 32 * 1024) bndu[i] = SENT;
}

// ---------------- pipelined strip DP: 32 blocks x 1 wave, 2 cells/lane/superstep ----------------
// XCD-aware mapping: block B -> xcd=B&7, slot=B>>3; dir=xcd>>2, strip=(xcd&3)*4+slot
// so strips 4k..4k+3 share an XCD (12/15 hops intra-XCD).
// Output: strip-local col-major a_sd[dirb][col][lane] -> every store is one 256B line.
__global__ __launch_bounds__(64)
void k_dp_strip(const float* __restrict__ W2, const int* __restrict__ ar,
                const int* __restrict__ en,
                float* __restrict__ a_sd, float* __restrict__ bnd) {
    __shared__ float ws_lds[256 * 64];          // [e][row], 64KB
    __shared__ float wi_s[1312];                // col = idx-128, valid 1..1023
    __shared__ int   en_s[1312];
    __shared__ float seed_s[1024];
    __shared__ float pub[2][32];                // bottom-row collect by column
    const int tid = threadIdx.x;
    const int B = blockIdx.x;                   // 0..31
    const int xcd = B & 7, slot = B >> 3;
    const int dir = xcd >> 2;
    const int b = ((xcd & 3) << 2) + slot;      // strip 0..15
    const int dirb = (dir << 4) + b;
    const bool fwd = (dir == 0);
    const bool seedstrip = (b == 0);
    const int rr = (b << 6) + tid;

    for (int x = tid; x < 1312; x += 64) {
        int col = x - 128;
        bool valid = (col >= 1 && col <= 1023);
        int e = valid ? en[fwd ? col : 1024 - col] : 0;
        en_s[x] = e;
        wi_s[x] = valid ? W2[AA + e] : 0.0f;
    }

    const int r_src = (rr >= 1) ? (fwd ? rr : (1024 - rr)) : 0;
    const float mywd2 = (rr >= 1) ? W2[ar[r_src]] : 0.0f;
    {   // stage this lane's substitution row into LDS [e][tid] (bank = tid%32, conflict-free)
        const float* wrow = W2 + AA + EE + ((rr >= 1) ? (ar[r_src] << 8) : 0);
        #pragma unroll 8
        for (int i = 0; i < 64; ++i) {
            float4 w = *(const float4*)(wrow + (i << 2));
            ws_lds[((i << 2) + 0) * 64 + tid] = w.x;
            ws_lds[((i << 2) + 1) * 64 + tid] = w.y;
            ws_lds[((i << 2) + 2) * 64 + tid] = w.z;
            ws_lds[((i << 2) + 3) * 64 + tid] = w.w;
        }
    }

    if (seedstrip) {   // seed_s[x] = sum_{c=1..x} wi_s[128+c]
        float loc[16]; float s = 0.0f;
        #pragma unroll
        for (int i = 0; i < 16; ++i) {
            int x = (tid << 4) + i;
            float w = (x >= 1) ? wi_s[128 + x] : 0.0f;
            s += w; loc[i] = s;
        }
        float cum = s;
        for (int off = 1; off < 64; off <<= 1) {
            float tt = __shfl_up(cum, off);
            if (tid >= off) cum += tt;
        }
        float excl = cum - s;
        #pragma unroll
        for (int i = 0; i < 16; ++i) seed_s[(tid << 4) + i] = excl + loc[i];
    }
    __syncthreads();

    float* __restrict__ sout = a_sd + (size_t)dirb * SSTRIDE + tid;   // [col<<6] offsets
    float* __restrict__ bnd_me = bnd + (size_t)dirb * 1024;
    const float* __restrict__ bnd_prev = bnd + (size_t)(dirb - 1) * 1024;
    const bool seedlane = seedstrip && (tid == 0);

    float vA = NINF, vB = NINF, upBp = NINF;
    int2   env[8];   // en pairs, prefetched 8 supersteps ahead
    float2 wiv[4];   // wi pairs, 4 ahead
    float2 wsv[4];   // ws pairs, 4 ahead
    #pragma unroll
    for (int s = 0; s < 8; ++s) env[s] = *(const int2*)&en_s[128 + 2 * s - 2 * tid];
    #pragma unroll
    for (int s = 0; s < 4; ++s) wiv[s] = *(const float2*)&wi_s[128 + 2 * s - 2 * tid];
    #pragma unroll
    for (int s = 0; s < 4; ++s)
        wsv[s] = make_float2(ws_lds[(env[s].x << 6) + tid], ws_lds[(env[s].y << 6) + tid]);

    float bvals = NINF;

    for (int c = 0; c < NCHUNKS; ++c) {
        // ---- fetch boundary cols 32c..32c+31 (consumer) ----
        if (c <= 31) {
            if (seedstrip) {
                bvals = seed_s[(c << 5) + (tid & 31)];
            } else {
                const float* src = bnd_prev + (c << 5) + (tid & 31);
                unsigned x;
                for (;;) {
                    asm volatile("global_load_dword %0, %1, off sc0 sc1\n\t"
                                 "s_waitcnt vmcnt(0)"
                                 : "=v"(x) : "v"(src) : "memory");
                    if (__ballot(x != SENT) == ~0ull) break;
                    __builtin_amdgcn_s_sleep(1);
                }
                bvals = __uint_as_float(x);
            }
        }
        #pragma unroll
        for (int k = 0; k < 16; ++k) {
            const int S = (c << 4) + k;
            const int sd = S - tid;                  // a = 2*sd
            const bool act = ((unsigned)sd < 512u);
            float bca = __int_as_float(__builtin_amdgcn_readlane(__float_as_int(bvals), 2 * k));
            float bcb = __int_as_float(__builtin_amdgcn_readlane(__float_as_int(bvals), 2 * k + 1));
            float upA = __int_as_float(__builtin_amdgcn_update_dpp(
                __float_as_int(bca), __float_as_int(vA), 0x138, 0xF, 0xF, false));
            float upB = __int_as_float(__builtin_amdgcn_update_dpp(
                __float_as_int(bcb), __float_as_int(vB), 0x138, 0xF, 0xF, false));
            float2 wsp = wsv[k & 3];
            float2 wip = wiv[k & 3];
            // software pipelines (issue early; LDS only)
            int2   ep  = *(const int2*)&en_s[128 + 2 * S + 16 - 2 * tid];    // for S+8
            float2 win = *(const float2*)&wi_s[128 + 2 * S + 8 - 2 * tid];   // for S+4
            int2   ec  = env[(k + 4) & 7];                                   // en for S+4
            float  wsx = ws_lds[(ec.x << 6) + tid];
            float  wsy = ws_lds[(ec.y << 6) + tid];

            // cell a
            float dela = mywd2 + upA;                // wd + V(r-1, a)
            float suba = wsp.x + upBp;               // ws[a] + V(r-1, a-1)
            float insa = wip.x + vB;                 // wi[a] + V(r, a-1)
            float VA = lse3(dela, suba, insa);
            VA = seedlane ? bca : VA;
            VA = act ? VA : NINF;
            // cell b = a+1
            float delb = mywd2 + upB;                // wd + V(r-1, b)
            float subb = wsp.y + upA;                // ws[b] + V(r-1, a)
            float insb = wip.y + VA;                 // wi[b] + V(r, a)
            float VB = lse3(delb, subb, insb);
            VB = seedlane ? bcb : VB;
            VB = act ? VB : NINF;

            env[(k + 8) & 7] = ep;
            wiv[(k + 4) & 3] = win;
            wsv[(k + 4) & 3] = make_float2(wsx, wsy);

            if (act) {
                const int a = 2 * sd;
                if (tid == 63)                        // bottom-row collect by column
                    *(float2*)&pub[(a >> 5) & 1][a & 31] = make_float2(VA, VB);
                float* st = sout + ((size_t)a << 6);  // [a][tid], [a+1][tid]: 256B lines
                st[0]  = VA;
                st[64] = VB;
            }
            upBp = upB; vA = VA; vB = VB;
        }
        // ---- publish col-chunk q=c-4 (complete as of superstep 16c+15) ----
        if (b < NSTRIP - 1 && c >= 4) {
            const int q = c - 4;
            float pv = pub[q & 1][tid & 31];
            if (tid < 32) {
                const float* dst = bnd_me + (q << 5) + tid;
                asm volatile("global_store_dword %0, %1, off sc0 sc1"
                             :: "v"(dst), "v"(__float_as_uint(pv)) : "memory");
            }
        }
    }
}

// ---------------- strip col-major -> row-major (fwd) / mirrored (bwd) ----------------
// a_sd[dirb][c][r]: dir 0: alpha[64b+r][c]   dir 1: beta[1023-(64b+r)][1023-c]
__global__ __launch_bounds__(256)
void k_striptr(const float* __restrict__ a_sd, float* __restrict__ outm, int dir) {
    __shared__ float tile[64][65];
    int b  = blockIdx.x;          // strip
    int ct = blockIdx.y;          // 64-col tile
    int lane = threadIdx.x & 63;
    int g    = threadIdx.x >> 6;  // 0..3
    const float* src = a_sd + ((size_t)(dir * NSTRIP + b)) * SSTRIDE + ((size_t)ct << 12);
    #pragma unroll
    for (int p = 0; p < 16; ++p) {
        int cl = (p << 2) + g;
        tile[cl][lane] = src[(cl << 6) + lane];   // coalesced 256B per col
    }
    __syncthreads();
    #pragma unroll
    for (int p = 0; p < 16; ++p) {
        int r = (p << 2) + g;
        int t = (b << 6) + r;
        int j = (ct << 6) + lane;
        float v = tile[lane][r];                  // banks (lane+r)%32: conflict-free
        if (!dir) outm[(size_t)t * 1024 + j] = v;
        else      outm[(size_t)(1023 - t) * 1024 + (1023 - j)] = v;
    }
}

// ---------------- block reduce helpers (256 threads = 4 waves) ----------------
__device__ __forceinline__ float blk_max(float v, float* sm) {
    for (int off = 32; off > 0; off >>= 1) v = fmaxf(v, __shfl_xor(v, off));
    if ((threadIdx.x & 63) == 0) sm[threadIdx.x >> 6] = v;
    __syncthreads();
    float r = fmaxf(fmaxf(sm[0], sm[1]), fmaxf(sm[2], sm[3]));
    __syncthreads();
    return r;
}
__device__ __forceinline__ float blk_sum(float v, float* sm) {
    for (int off = 32; off > 0; off >>= 1) v += __shfl_xor(v, off);
    if ((threadIdx.x & 63) == 0) sm[threadIdx.x >> 6] = v;
    __syncthreads();
    float r = sm[0] + sm[1] + sm[2] + sm[3];
    __syncthreads();
    return r;
}

// ---------------- fused: rowred[t] (delete LSE) + substitution atomicMax ----------------
__global__ __launch_bounds__(256)
void k_red1(const float* __restrict__ alpha, const float* __restrict__ beta,
            const int* __restrict__ ar, const int* __restrict__ en,
            float* __restrict__ rowred, unsigned* __restrict__ mkey) {
    __shared__ float sm[4];
    int t = 1 + blockIdx.x;
    int tid = threadIdx.x;
    int base = AA + EE + (ar[t] << 8);
    float v[4]; float m = NINF;
    #pragma unroll
    for (int i = 0; i < 4; ++i) {
        int j = tid + (i << 8);
        float b_ = beta[(size_t)t * VV + j];
        v[i] = alpha[(size_t)(t - 1) * VV + j] + b_;
        m = fmaxf(m, v[i]);
        if (j >= 1) {
            float vs = alpha[(size_t)(t - 1) * VV + (j - 1)] + b_;
            atomicMax(&mkey[base + en[j]], fkey(vs));
        }
    }
    m = blk_max(m, sm);
    float s = 0.0f;
    #pragma unroll
    for (int i = 0; i < 4; ++i) s += E2(v[i] - m);
    s = blk_sum(s, sm);
    if (tid == 0) rowred[t] = m + L2(s);
}

// ---------------- insert col reduction, stage 1: partials over 128-row bands ----------------
__global__ __launch_bounds__(256)
void k_colpart(const float* __restrict__ alpha, const float* __restrict__ beta,
               float* __restrict__ cpm, float* __restrict__ cps) {
    __shared__ float smm[4][64], sms[4][64];
    int c = threadIdx.x & 63;
    int g = threadIdx.x >> 6;
    int j = (blockIdx.x << 6) + c;
    int t0 = blockIdx.y << 7;
    float m = NINF, s = 0.0f;
    if (j >= 1) {
        for (int t = t0 + g; t < t0 + 128; t += 4) {
            float v = alpha[(size_t)t * 1024 + (j - 1)] + beta[(size_t)t * 1024 + j];
            if (v <= m) s += E2(v - m);
            else { s = s * E2(m - v) + 1.0f; m = v; }
        }
    }
    smm[g][c] = m; sms[g][c] = s;
    __syncthreads();
    if (g == 0) {
        float M = m, S = s;
        for (int k = 1; k < 4; ++k) {
            float mk = smm[k][c], sk = sms[k][c];
            if (mk <= M) S += sk * E2(mk - M);
            else { S = S * E2(M - mk) + sk; M = mk; }
        }
        cpm[(size_t)blockIdx.y * 1024 + j] = M;
        cps[(size_t)blockIdx.y * 1024 + j] = S;
    }
}
// stage 2: merge 8 bands
__global__ void k_colfin(const float* __restrict__ cpm, const float* __restrict__ cps,
                         float* __restrict__ colred) {
    int j = blockIdx.x * 256 + threadIdx.x;
    float M = NINF, S = 0.0f;
    for (int k = 0; k < 8; ++k) {
        float mk = cpm[(size_t)k * 1024 + j], sk = cps[(size_t)k * 1024 + j];
        if (mk <= M) S += sk * E2(mk - M);
        else { S = S * E2(M - mk) + sk; M = mk; }
    }
    colred[j] = (j >= 1) ? (M + L2(S)) : NINF;
}

// ---------------- substitution bins: sum pass (needs mkey) ----------------
__global__ void k_ssum(const float* __restrict__ alpha, const float* __restrict__ beta,
                       const int* __restrict__ ar, const int* __restrict__ en,
                       const unsigned* __restrict__ mkey, float* __restrict__ sbuf) {
    int t = 1 + blockIdx.x;
    int base = AA + EE + (ar[t] << 8);
    for (int j = 1 + threadIdx.x; j <= VV - 1; j += 256) {
        float v = alpha[(size_t)(t - 1) * VV + (j - 1)] + beta[(size_t)t * VV + j];
        int b = base + en[j];
        atomicAdd(&sbuf[b], E2(v - fdec(mkey[b])));
    }
}

// ---------------- finalize: sub bins (blocks 0..255), dbins (256), ibins (257) ----------------
__global__ __launch_bounds__(256)
void k_fin(const unsigned* __restrict__ mkey, const float* __restrict__ sbuf,
           const float* __restrict__ W, const int* __restrict__ ar,
           const int* __restrict__ en, const float* __restrict__ rowred,
           const float* __restrict__ colred, float* __restrict__ out) {
    __shared__ float fv[1024];
    __shared__ int   iv[1024];
    int blk = blockIdx.x;
    int tid = threadIdx.x;
    if (blk < 256) {
        int id = AA + EE + blk * 256 + tid;
        unsigned key = mkey[id];
        float v = (key > KEY_NEGINF) ? (W[id] + LN2F * (fdec(key) + L2(sbuf[id]))) : NEGBIG;
        out[id] = safe_out(v);
        return;
    }
    const bool isd = (blk == 256);
    for (int x = tid; x < 1024; x += 256) {
        fv[x] = isd ? rowred[x] : colred[x];
        iv[x] = isd ? ar[x] : en[x];
    }
    __syncthreads();
    float m = NINF, s = 0.0f;
    for (int t = 1; t < 1024; ++t) {
        if (iv[t] == tid) {
            float v = fv[t];
            if (v <= m) s += E2(v - m);
            else { s = s * E2(m - v) + 1.0f; m = v; }
        }
    }
    int oid = isd ? tid : (AA + tid);
    float v = (m == NINF) ? NEGBIG : (W[oid] + LN2F * (m + L2(s)));
    out[oid] = safe_out(v);
}

extern "C" void kernel_launch(void* const* d_in, const int* in_sizes, int n_in,
                              void* d_out, int out_size, void* d_ws, size_t ws_size,
                              hipStream_t stream) {
    const float* W  = (const float*)d_in[0];
    const int*   ar = (const int*)d_in[1];
    const int*   en = (const int*)d_in[2];
    float* out = (float*)d_out;

    char* p = (char*)d_ws;
    float* W2      = (float*)p; p += (size_t)CC * 4;
    float* a_sd    = (float*)p; p += (size_t)32 * SSTRIDE * 4;   // 8MB strip col-major
    float* alpha   = (float*)p; p += (size_t)TT * VV * 4;
    float* beta    = (float*)p; p += (size_t)TT * VV * 4;
    float* bnd     = (float*)p; p += (size_t)32 * 1024 * 4;
    float* rowred  = (float*)p; p += TT * 4;
    float* colred  = (float*)p; p += VV * 4;
    float* cpm     = (float*)p; p += (size_t)8 * 1024 * 4;
    float* cps     = (float*)p; p += (size_t)8 * 1024 * 4;
    float* sbuf    = (float*)p; p += (size_t)CC * 4;
    unsigned* mkey = (unsigned*)p; p += (size_t)CC * 4;

    k_init<<<dim3((CC + 255) / 256), dim3(256), 0, stream>>>(W, W2, mkey, sbuf, (unsigned*)bnd);
    k_dp_strip<<<dim3(32), dim3(64), 0, stream>>>(W2, ar, en, a_sd, bnd);
    k_striptr<<<dim3(16, 16), dim3(256), 0, stream>>>(a_sd, alpha, 0);
    k_striptr<<<dim3(16, 16), dim3(256), 0, stream>>>(a_sd, beta, 1);
    k_red1<<<dim3(TT - 1), dim3(256), 0, stream>>>(alpha, beta, ar, en, rowred, mkey);
    k_colpart<<<dim3(16, 8), dim3(256), 0, stream>>>(alpha, beta, cpm, cps);
    k_colfin<<<dim3(4), dim3(256), 0, stream>>>(cpm, cps, colred);
    k_ssum<<<dim3(TT - 1), dim3(256), 0, stream>>>(alpha, beta, ar, en, mkey, sbuf);
    k_fin<<<dim3(258), dim3(256), 0, stream>>>(mkey, sbuf, W, ar, en, rowred, colred, out);
}